// Round 8
// baseline (64.182 us; speedup 1.0000x reference)
//
#include <hip/hip_runtime.h>

// QuadraticWeightedKappa: N=4194304 rows x 5 classes (f32 logits), int32
// targets. Output: one f32 scalar -kappa.
//
// Correctness model (locked in R5, absmax=0.0): counts = first-max-wins raw
// argmax; finalize = f32 XLA-CPU pipeline with SEQUENTIAL l2r 25-elem sums.
//
// Perf history:
//  R5 56us hist: address-divergent loads (80B lane stride).
//  R6 210us REGRESSION: per-block __threadfence + 8-way LDS read conflicts.
//  R7 36.3us total (~30us hist): LDS staging, conflict-free reads, but 1024
//     blocks x 4 serial stages x 2 barriers = latency-exposed (~50% of the
//     6.9 TB/s streaming ceiling measured on the harness's own 327MB fill).
//  R8: one 1024-row tile per block, 4096 blocks, 2 barriers/block ->
//     max cross-block overlap for latency hiding.
//
// LDS banks: writes linear ds_write_b128 (conflict-free); reads at byte
// 20*(r*256+tid): lane stride 5 dwords, gcd(5,32)=1 -> 2-way aliasing = free.

#define KCLS 5

__global__ __launch_bounds__(256) void kappa_hist(const float* __restrict__ x,
                                                  const int* __restrict__ tgt,
                                                  unsigned int* __restrict__ gcnt) {
    __shared__ float lds[5120];       // 1024 rows x 5 floats = 20 KB
    __shared__ unsigned int h[128];   // 4 waves x 32-slot histograms
    const int tid = threadIdx.x;
    if (tid < 128) h[tid] = 0u;

    const float4* xv = (const float4*)x;
    const int r0 = blockIdx.x * 1024;        // 1024 rows per block
    const int bv4 = (r0 >> 2) * 5;           // float4 index of tile start

    // coalesced: lane-stride 16B
    float4 v0 = xv[bv4 + 0 * 256 + tid];
    float4 v1 = xv[bv4 + 1 * 256 + tid];
    float4 v2 = xv[bv4 + 2 * 256 + tid];
    float4 v3 = xv[bv4 + 3 * 256 + tid];
    float4 v4 = xv[bv4 + 4 * 256 + tid];
    // targets for the rows this thread scores (coalesced dword loads)
    const int tg0 = tgt[r0 + 0 * 256 + tid];
    const int tg1 = tgt[r0 + 1 * 256 + tid];
    const int tg2 = tgt[r0 + 2 * 256 + tid];
    const int tg3 = tgt[r0 + 3 * 256 + tid];

    float4* lf = (float4*)lds;        // linear b128 writes: conflict-free
    lf[0 * 256 + tid] = v0;
    lf[1 * 256 + tid] = v1;
    lf[2 * 256 + tid] = v2;
    lf[3 * 256 + tid] = v3;
    lf[4 * 256 + tid] = v4;
    __syncthreads();                  // staged data + h init visible

    unsigned int* hw = h + ((tid >> 6) << 5);
    const int tgv[4] = {tg0, tg1, tg2, tg3};
#pragma unroll
    for (int r = 0; r < 4; ++r) {
        // row (r*256 + tid): dword lane-stride 5 -> 2-way banks (free)
        const float* fr = lds + (r * 256 + tid) * 5;
        float m = fr[0];
        int k = 0;
#pragma unroll
        for (int j = 1; j < KCLS; ++j)
            if (fr[j] > m) { m = fr[j]; k = j; }
        atomicAdd(&hw[tgv[r] * KCLS + k], 1u);
    }
    __syncthreads();

    if (tid < KCLS * KCLS) {
        unsigned int s = h[tid] + h[32 + tid] + h[64 + tid] + h[96 + tid];
        if (s) atomicAdd(&gcnt[tid], s);
    }
}

// XLA CPU full-reduce: init 0.0f, sequential left-to-right adds.
__device__ __forceinline__ float seq25(const float* a) {
    float res = 0.0f;
#pragma unroll
    for (int i = 0; i < 25; ++i) res = __fadd_rn(res, a[i]);
    return res;
}

__global__ void kappa_finalize(const unsigned int* __restrict__ cnt,
                               float* __restrict__ out, int n) {
    if (threadIdx.x != 0 || blockIdx.x != 0) return;

    const float fn = (float)n;  // 2^22, exact
    float conf[25];
#pragma unroll
    for (int k = 0; k < 25; ++k)
        conf[k] = __fdiv_rn((float)cnt[k], fn);  // exact

    float w[25];
#pragma unroll
    for (int i = 0; i < KCLS; ++i)
#pragma unroll
        for (int j = 0; j < KCLS; ++j)
            w[i * KCLS + j] = (float)((i - j) * (i - j)) / 16.0f;  // exact

    float mt[KCLS], mp[KCLS];
#pragma unroll
    for (int i = 0; i < KCLS; ++i) {
        float s = 0.0f;
#pragma unroll
        for (int j = 0; j < KCLS; ++j) s = __fadd_rn(s, conf[i * KCLS + j]);
        mt[i] = s;  // exact: multiples of 2^-22
    }
#pragma unroll
    for (int j = 0; j < KCLS; ++j) {
        float s = 0.0f;
#pragma unroll
        for (int i = 0; i < KCLS; ++i) s = __fadd_rn(s, conf[i * KCLS + j]);
        mp[j] = s;
    }

    float a[25], b[25];
#pragma unroll
    for (int k = 0; k < 25; ++k) {
        a[k] = __fmul_rn(conf[k], w[k]);                 // RN mul (no FMA)
        float e = __fmul_rn(mt[k / KCLS], mp[k % KCLS]); // outer, RN
        b[k] = __fmul_rn(e, w[k]);                       // RN mul
    }

    float num = seq25(a);
    float den = seq25(b);
    float den2 = __fadd_rn(den, 1e-7f);   // weak scalar -> f32
    float q = __fdiv_rn(num, den2);
    float kappa = __fsub_rn(1.0f, q);
    out[0] = -kappa;
}

extern "C" void kernel_launch(void* const* d_in, const int* in_sizes, int n_in,
                              void* d_out, int out_size, void* d_ws, size_t ws_size,
                              hipStream_t stream) {
    const float* x = (const float*)d_in[0];
    const int* tgt = (const int*)d_in[1];
    float* out = (float*)d_out;
    unsigned int* cnt = (unsigned int*)d_ws;

    const int n = in_sizes[1];          // rows (4194304 = 2^22)
    const int nblocks = n / 1024;       // 4096 blocks, 1024 rows each (exact)

    hipMemsetAsync(cnt, 0, 32 * sizeof(unsigned int), stream);
    kappa_hist<<<nblocks, 256, 0, stream>>>(x, tgt, cnt);
    kappa_finalize<<<1, 64, 0, stream>>>(cnt, out, n);
}

// Round 9
// 29.160 us; speedup vs baseline: 2.2010x; 2.2010x over previous
//
#include <hip/hip_runtime.h>

// QuadraticWeightedKappa: N=4194304 rows x 5 classes (f32 logits), int32
// targets. Output: one f32 scalar -kappa.
//
// Correctness model (locked in R5, absmax=0.0): counts = first-max-wins raw
// argmax; finalize = f32 XLA-CPU pipeline with SEQUENTIAL l2r 25-elem sums.
//
// Perf history:
//  R5 56us / R8 59us: duration identical cold (49MB HBM fetch) vs warm
//    (0 fetch), identical across divergent vs staged load patterns, but
//    halves when block count drops 4096->1024 (R7, 30us). Diagnosis: 4096
//    blocks x 25 global atomics to the SAME two cache lines = ~102K
//    serialized L2 RMWs ~ 43us floor. The load pattern was never the
//    post-R7 limiter; the shared counter array was.
//  R9: 64 replica counter arrays, 256B apart (distinct lines/L2 channels);
//    block uses replica blockIdx&63 -> ~64x less per-line contention.
//    Streaming structure unchanged from R8 (4096 blocks, 1 tile, 2 barriers).
//
// LDS banks: writes linear ds_write_b128 (conflict-free); reads at byte
// 20*(r*256+tid): lane stride 5 dwords, gcd(5,32)=1 -> 2-way aliasing = free.
//
// ws layout: 64 replicas x 64 dwords (bins 0..24 used) = 16 KB.

#define KCLS 5
#define NREP 64

__global__ __launch_bounds__(256) void kappa_hist(const float* __restrict__ x,
                                                  const int* __restrict__ tgt,
                                                  unsigned int* __restrict__ gcnt) {
    __shared__ float lds[5120];       // 1024 rows x 5 floats = 20 KB
    __shared__ unsigned int h[128];   // 4 waves x 32-slot histograms
    const int tid = threadIdx.x;
    if (tid < 128) h[tid] = 0u;

    const float4* xv = (const float4*)x;
    const int r0 = blockIdx.x * 1024;        // 1024 rows per block
    const int bv4 = (r0 >> 2) * 5;           // float4 index of tile start

    // coalesced: lane-stride 16B
    float4 v0 = xv[bv4 + 0 * 256 + tid];
    float4 v1 = xv[bv4 + 1 * 256 + tid];
    float4 v2 = xv[bv4 + 2 * 256 + tid];
    float4 v3 = xv[bv4 + 3 * 256 + tid];
    float4 v4 = xv[bv4 + 4 * 256 + tid];
    // targets for the rows this thread scores (coalesced dword loads)
    const int tg0 = tgt[r0 + 0 * 256 + tid];
    const int tg1 = tgt[r0 + 1 * 256 + tid];
    const int tg2 = tgt[r0 + 2 * 256 + tid];
    const int tg3 = tgt[r0 + 3 * 256 + tid];

    float4* lf = (float4*)lds;        // linear b128 writes: conflict-free
    lf[0 * 256 + tid] = v0;
    lf[1 * 256 + tid] = v1;
    lf[2 * 256 + tid] = v2;
    lf[3 * 256 + tid] = v3;
    lf[4 * 256 + tid] = v4;
    __syncthreads();                  // staged data + h init visible

    unsigned int* hw = h + ((tid >> 6) << 5);
    const int tgv[4] = {tg0, tg1, tg2, tg3};
#pragma unroll
    for (int r = 0; r < 4; ++r) {
        // row (r*256 + tid): dword lane-stride 5 -> 2-way banks (free)
        const float* fr = lds + (r * 256 + tid) * 5;
        float m = fr[0];
        int k = 0;
#pragma unroll
        for (int j = 1; j < KCLS; ++j)
            if (fr[j] > m) { m = fr[j]; k = j; }
        atomicAdd(&hw[tgv[r] * KCLS + k], 1u);
    }
    __syncthreads();

    if (tid < KCLS * KCLS) {
        unsigned int s = h[tid] + h[32 + tid] + h[64 + tid] + h[96 + tid];
        // replica spread: 64 blocks share a replica; replicas 256B apart
        if (s) atomicAdd(&gcnt[(blockIdx.x & (NREP - 1)) * 64 + tid], s);
    }
}

// XLA CPU full-reduce: init 0.0f, sequential left-to-right adds.
__device__ __forceinline__ float seq25(const float* a) {
    float res = 0.0f;
#pragma unroll
    for (int i = 0; i < 25; ++i) res = __fadd_rn(res, a[i]);
    return res;
}

__global__ void kappa_finalize(const unsigned int* __restrict__ gcnt,
                               float* __restrict__ out, int n) {
    __shared__ unsigned int cnt[25];
    const int tid = threadIdx.x;
    if (blockIdx.x != 0) return;

    if (tid < 25) {
        unsigned int s = 0;
#pragma unroll
        for (int r = 0; r < NREP; ++r) s += gcnt[r * 64 + tid];  // independent loads
        cnt[tid] = s;
    }
    __syncthreads();
    if (tid != 0) return;

    const float fn = (float)n;  // 2^22, exact
    float conf[25];
#pragma unroll
    for (int k = 0; k < 25; ++k)
        conf[k] = __fdiv_rn((float)cnt[k], fn);  // exact

    float w[25];
#pragma unroll
    for (int i = 0; i < KCLS; ++i)
#pragma unroll
        for (int j = 0; j < KCLS; ++j)
            w[i * KCLS + j] = (float)((i - j) * (i - j)) / 16.0f;  // exact

    float mt[KCLS], mp[KCLS];
#pragma unroll
    for (int i = 0; i < KCLS; ++i) {
        float s = 0.0f;
#pragma unroll
        for (int j = 0; j < KCLS; ++j) s = __fadd_rn(s, conf[i * KCLS + j]);
        mt[i] = s;  // exact: multiples of 2^-22
    }
#pragma unroll
    for (int j = 0; j < KCLS; ++j) {
        float s = 0.0f;
#pragma unroll
        for (int i = 0; i < KCLS; ++i) s = __fadd_rn(s, conf[i * KCLS + j]);
        mp[j] = s;
    }

    float a[25], b[25];
#pragma unroll
    for (int k = 0; k < 25; ++k) {
        a[k] = __fmul_rn(conf[k], w[k]);                 // RN mul (no FMA)
        float e = __fmul_rn(mt[k / KCLS], mp[k % KCLS]); // outer, RN
        b[k] = __fmul_rn(e, w[k]);                       // RN mul
    }

    float num = seq25(a);
    float den = seq25(b);
    float den2 = __fadd_rn(den, 1e-7f);   // weak scalar -> f32
    float q = __fdiv_rn(num, den2);
    float kappa = __fsub_rn(1.0f, q);
    out[0] = -kappa;
}

extern "C" void kernel_launch(void* const* d_in, const int* in_sizes, int n_in,
                              void* d_out, int out_size, void* d_ws, size_t ws_size,
                              hipStream_t stream) {
    const float* x = (const float*)d_in[0];
    const int* tgt = (const int*)d_in[1];
    float* out = (float*)d_out;
    unsigned int* cnt = (unsigned int*)d_ws;

    const int n = in_sizes[1];          // rows (4194304 = 2^22)
    const int nblocks = n / 1024;       // 4096 blocks, 1024 rows each (exact)

    hipMemsetAsync(cnt, 0, NREP * 64 * sizeof(unsigned int), stream);
    kappa_hist<<<nblocks, 256, 0, stream>>>(x, tgt, cnt);
    kappa_finalize<<<1, 64, 0, stream>>>(cnt, out, n);
}

// Round 10
// 28.613 us; speedup vs baseline: 2.2431x; 1.0191x over previous
//
#include <hip/hip_runtime.h>

// QuadraticWeightedKappa: N=4194304 rows x 5 classes (f32 logits), int32
// targets. Output: one f32 scalar -kappa.
//
// Correctness model (locked in R5, absmax=0.0): counts = first-max-wins raw
// argmax; finalize = f32 XLA-CPU pipeline with SEQUENTIAL l2r 25-elem sums.
//
// Perf history:
//  R5 56us hist = ~43us atomic serialization (4096 blocks x 25 atomics to 2
//    cache lines) + ~13us streaming. Divergent loads were NEVER the limiter
//    (line-request math: 5.2M reqs / 256 CU / 2.4GHz ~ 3.6us).
//  R6 210us: per-block __threadfence => cross-XCD invalidate storm.
//  R9 29.2us total: 64 replica counter arrays killed the atomic floor;
//    hist ~22us, still above the 14.6us streaming floor (100.7MB @ 6.9TB/s,
//    ceiling measured on the harness's own 327MB poison fill).
//  R10: remove the LDS transpose + its block-wide barrier (each block's
//    waves serialized on staged-load completion). Direct per-thread row
//    loads (80B lane stride), wave-local histogram init (LDS per-wave FIFO
//    ordering => no init barrier), ONE barrier before the replica merge.
//
// ws layout: 64 replicas x 64 dwords (bins 0..24 used) = 16 KB.

#define KCLS 5
#define NREP 64

__global__ __launch_bounds__(256) void kappa_hist(const float* __restrict__ x,
                                                  const int* __restrict__ tgt,
                                                  unsigned int* __restrict__ gcnt) {
    __shared__ unsigned int h[128];   // 4 waves x 32-slot histograms
    const int tid = threadIdx.x;
    const int lane = tid & 63;
    unsigned int* hw = h + ((tid >> 6) << 5);
    if (lane < 32) hw[lane] = 0u;     // wave-local init; LDS ops are FIFO
                                      // per-wave -> later ds_add is ordered

    const int t = blockIdx.x * 256 + tid;   // 4 rows/thread
    const float4* xv = (const float4*)x;
    float f[20];
#pragma unroll
    for (int k = 0; k < 5; ++k) {
        float4 v = xv[t * 5 + k];     // 80B lane stride: proven non-limiting
        f[4 * k + 0] = v.x;
        f[4 * k + 1] = v.y;
        f[4 * k + 2] = v.z;
        f[4 * k + 3] = v.w;
    }
    const int4 tg = ((const int4*)tgt)[t];  // 16B lane stride: coalesced
    const int tgv[4] = {tg.x, tg.y, tg.z, tg.w};
#pragma unroll
    for (int r = 0; r < 4; ++r) {
        const float* fr = f + 5 * r;
        // first-occurrence argmax (strict >) == argmax(softmax32(x))
        float m = fr[0];
        int k = 0;
#pragma unroll
        for (int j = 1; j < KCLS; ++j)
            if (fr[j] > m) { m = fr[j]; k = j; }
        atomicAdd(&hw[tgv[r] * KCLS + k], 1u);
    }
    __syncthreads();                  // the ONLY barrier: merge waves

    if (tid < KCLS * KCLS) {
        unsigned int s = h[tid] + h[32 + tid] + h[64 + tid] + h[96 + tid];
        // replica spread: 64 blocks share a replica; replicas 256B apart
        if (s) atomicAdd(&gcnt[(blockIdx.x & (NREP - 1)) * 64 + tid], s);
    }
}

// XLA CPU full-reduce: init 0.0f, sequential left-to-right adds.
__device__ __forceinline__ float seq25(const float* a) {
    float res = 0.0f;
#pragma unroll
    for (int i = 0; i < 25; ++i) res = __fadd_rn(res, a[i]);
    return res;
}

__global__ void kappa_finalize(const unsigned int* __restrict__ gcnt,
                               float* __restrict__ out, int n) {
    __shared__ unsigned int cnt[25];
    const int tid = threadIdx.x;
    if (blockIdx.x != 0) return;

    if (tid < 25) {
        unsigned int s = 0;
#pragma unroll
        for (int r = 0; r < NREP; ++r) s += gcnt[r * 64 + tid];  // independent loads
        cnt[tid] = s;
    }
    __syncthreads();
    if (tid != 0) return;

    const float fn = (float)n;  // 2^22, exact
    float conf[25];
#pragma unroll
    for (int k = 0; k < 25; ++k)
        conf[k] = __fdiv_rn((float)cnt[k], fn);  // exact

    float w[25];
#pragma unroll
    for (int i = 0; i < KCLS; ++i)
#pragma unroll
        for (int j = 0; j < KCLS; ++j)
            w[i * KCLS + j] = (float)((i - j) * (i - j)) / 16.0f;  // exact

    float mt[KCLS], mp[KCLS];
#pragma unroll
    for (int i = 0; i < KCLS; ++i) {
        float s = 0.0f;
#pragma unroll
        for (int j = 0; j < KCLS; ++j) s = __fadd_rn(s, conf[i * KCLS + j]);
        mt[i] = s;  // exact: multiples of 2^-22
    }
#pragma unroll
    for (int j = 0; j < KCLS; ++j) {
        float s = 0.0f;
#pragma unroll
        for (int i = 0; i < KCLS; ++i) s = __fadd_rn(s, conf[i * KCLS + j]);
        mp[j] = s;
    }

    float a[25], b[25];
#pragma unroll
    for (int k = 0; k < 25; ++k) {
        a[k] = __fmul_rn(conf[k], w[k]);                 // RN mul (no FMA)
        float e = __fmul_rn(mt[k / KCLS], mp[k % KCLS]); // outer, RN
        b[k] = __fmul_rn(e, w[k]);                       // RN mul
    }

    float num = seq25(a);
    float den = seq25(b);
    float den2 = __fadd_rn(den, 1e-7f);   // weak scalar -> f32
    float q = __fdiv_rn(num, den2);
    float kappa = __fsub_rn(1.0f, q);
    out[0] = -kappa;
}

extern "C" void kernel_launch(void* const* d_in, const int* in_sizes, int n_in,
                              void* d_out, int out_size, void* d_ws, size_t ws_size,
                              hipStream_t stream) {
    const float* x = (const float*)d_in[0];
    const int* tgt = (const int*)d_in[1];
    float* out = (float*)d_out;
    unsigned int* cnt = (unsigned int*)d_ws;

    const int n = in_sizes[1];          // rows (4194304 = 2^22)
    const int nblocks = n / 1024;       // 4096 blocks, 1024 rows each (exact)

    hipMemsetAsync(cnt, 0, NREP * 64 * sizeof(unsigned int), stream);
    kappa_hist<<<nblocks, 256, 0, stream>>>(x, tgt, cnt);
    kappa_finalize<<<1, 64, 0, stream>>>(cnt, out, n);
}

// Round 11
// 28.260 us; speedup vs baseline: 2.2711x; 1.0125x over previous
//
#include <hip/hip_runtime.h>

// QuadraticWeightedKappa: N=4194304 rows x 5 classes (f32 logits), int32
// targets. Output: one f32 scalar -kappa.
//
// Correctness model (locked in R5, absmax=0.0): counts = first-max-wins raw
// argmax; finalize = f32 XLA-CPU pipeline with SEQUENTIAL l2r 25-elem sums.
//
// Perf history:
//  R5/R8 ~56-59us hist: 4096 blocks x 25 atomics on 2 cache lines = ~43us
//    serialized L2 RMW floor. Fixed in R9 (64 replica arrays, 256B apart).
//  R6 210us: per-block __threadfence => cross-XCD invalidate storm. Reverted.
//  R9 29.2 / R10 28.6 total: hist ~22-23us both, vs ~15-16us streaming
//    floor. R10 residual = TCP line-divergence (80B lane stride: 64 lines
//    per load instr, ~9us/CU request processing). R9 residual = block-wide
//    stage->consume barrier (4 waves serialized on slowest load).
//  R11: wave-private staging kills both: coalesced loads + linear
//    ds_write_b128 into a PER-WAVE region, consumed by the same wave only
//    => compiler's lgkmcnt(0) suffices, NO barrier before consume; waves
//    run fully decoupled. One barrier remains (end-of-block merge).
//
// LDS: stage reads at dword (5*lane + j) mod 32: gcd(5,32)=1 -> 2-way bank
// aliasing (free, m136). Writes: linear b128 (canonical conflict-free).
//
// ws layout: 64 replicas x 64 dwords (bins 0..24 used) = 16 KB.

#define KCLS 5
#define NREP 64

__global__ __launch_bounds__(256) void kappa_hist(const float* __restrict__ x,
                                                  const int* __restrict__ tgt,
                                                  unsigned int* __restrict__ gcnt) {
    __shared__ float lds[5120];       // 4 wave-regions x 1280 dwords (20 KB)
    __shared__ unsigned int h[128];   // 4 waves x 32-slot histograms
    const int tid = threadIdx.x;
    const int lane = tid & 63;
    const int w = tid >> 6;
    unsigned int* hw = h + (w << 5);
    if (lane < 32) hw[lane] = 0u;     // wave-local init (lgkmcnt-ordered
                                      // before this wave's LDS atomics)

    // ---- wave-private staging: this wave's 256 rows = 320 float4 chunks
    const float4* xv = (const float4*)x;
    const int gf4 = blockIdx.x * 1280 + w * 320 + lane;  // float4 index
    float4 v0 = xv[gf4 + 0 * 64];     // 16B lane stride: coalesced
    float4 v1 = xv[gf4 + 1 * 64];
    float4 v2 = xv[gf4 + 2 * 64];
    float4 v3 = xv[gf4 + 3 * 64];
    float4 v4 = xv[gf4 + 4 * 64];

    const int gr = blockIdx.x * 1024 + w * 256 + lane;   // this wave's rows
    const int t0 = tgt[gr + 0 * 64];  // 4B lane stride: coalesced
    const int t1 = tgt[gr + 1 * 64];
    const int t2 = tgt[gr + 2 * 64];
    const int t3 = tgt[gr + 3 * 64];

    float* wbase = lds + w * 1280;
    float4* lf = (float4*)wbase;      // linear b128 writes: conflict-free
    lf[0 * 64 + lane] = v0;
    lf[1 * 64 + lane] = v1;
    lf[2 * 64 + lane] = v2;
    lf[3 * 64 + lane] = v3;
    lf[4 * 64 + lane] = v4;
    // NO __syncthreads: wave reads only its own region; the compiler's
    // mandatory lgkmcnt wait (LDS RAW alias) gives cross-lane visibility
    // within the wave (LDS is physically shared, ops retire into the array).

    const int tgv[4] = {t0, t1, t2, t3};
#pragma unroll
    for (int m = 0; m < 4; ++m) {
        // row 64m+lane: dword lane-stride 5 -> 2-way banks (free)
        const float* fr = wbase + (m * 64 + lane) * 5;
        float mx = fr[0];
        int k = 0;
#pragma unroll
        for (int j = 1; j < KCLS; ++j)
            if (fr[j] > mx) { mx = fr[j]; k = j; }   // first-max-wins
        atomicAdd(&hw[tgv[m] * KCLS + k], 1u);
    }
    __syncthreads();                  // the ONLY barrier: merge waves

    if (tid < KCLS * KCLS) {
        unsigned int s = h[tid] + h[32 + tid] + h[64 + tid] + h[96 + tid];
        // replica spread: 64 blocks share a replica; replicas 256B apart
        if (s) atomicAdd(&gcnt[(blockIdx.x & (NREP - 1)) * 64 + tid], s);
    }
}

// XLA CPU full-reduce: init 0.0f, sequential left-to-right adds.
__device__ __forceinline__ float seq25(const float* a) {
    float res = 0.0f;
#pragma unroll
    for (int i = 0; i < 25; ++i) res = __fadd_rn(res, a[i]);
    return res;
}

__global__ void kappa_finalize(const unsigned int* __restrict__ gcnt,
                               float* __restrict__ out, int n) {
    __shared__ unsigned int cnt[25];
    const int tid = threadIdx.x;
    if (blockIdx.x != 0) return;

    if (tid < 25) {
        unsigned int s = 0;
#pragma unroll
        for (int r = 0; r < NREP; ++r) s += gcnt[r * 64 + tid];  // independent loads
        cnt[tid] = s;
    }
    __syncthreads();
    if (tid != 0) return;

    const float fn = (float)n;  // 2^22, exact
    float conf[25];
#pragma unroll
    for (int k = 0; k < 25; ++k)
        conf[k] = __fdiv_rn((float)cnt[k], fn);  // exact

    float w[25];
#pragma unroll
    for (int i = 0; i < KCLS; ++i)
#pragma unroll
        for (int j = 0; j < KCLS; ++j)
            w[i * KCLS + j] = (float)((i - j) * (i - j)) / 16.0f;  // exact

    float mt[KCLS], mp[KCLS];
#pragma unroll
    for (int i = 0; i < KCLS; ++i) {
        float s = 0.0f;
#pragma unroll
        for (int j = 0; j < KCLS; ++j) s = __fadd_rn(s, conf[i * KCLS + j]);
        mt[i] = s;  // exact: multiples of 2^-22
    }
#pragma unroll
    for (int j = 0; j < KCLS; ++j) {
        float s = 0.0f;
#pragma unroll
        for (int i = 0; i < KCLS; ++i) s = __fadd_rn(s, conf[i * KCLS + j]);
        mp[j] = s;
    }

    float a[25], b[25];
#pragma unroll
    for (int k = 0; k < 25; ++k) {
        a[k] = __fmul_rn(conf[k], w[k]);                 // RN mul (no FMA)
        float e = __fmul_rn(mt[k / KCLS], mp[k % KCLS]); // outer, RN
        b[k] = __fmul_rn(e, w[k]);                       // RN mul
    }

    float num = seq25(a);
    float den = seq25(b);
    float den2 = __fadd_rn(den, 1e-7f);   // weak scalar -> f32
    float q = __fdiv_rn(num, den2);
    float kappa = __fsub_rn(1.0f, q);
    out[0] = -kappa;
}

extern "C" void kernel_launch(void* const* d_in, const int* in_sizes, int n_in,
                              void* d_out, int out_size, void* d_ws, size_t ws_size,
                              hipStream_t stream) {
    const float* x = (const float*)d_in[0];
    const int* tgt = (const int*)d_in[1];
    float* out = (float*)d_out;
    unsigned int* cnt = (unsigned int*)d_ws;

    const int n = in_sizes[1];          // rows (4194304 = 2^22)
    const int nblocks = n / 1024;       // 4096 blocks, 1024 rows each (exact)

    hipMemsetAsync(cnt, 0, NREP * 64 * sizeof(unsigned int), stream);
    kappa_hist<<<nblocks, 256, 0, stream>>>(x, tgt, cnt);
    kappa_finalize<<<1, 64, 0, stream>>>(cnt, out, n);
}